// Round 1
// baseline (232.147 us; speedup 1.0000x reference)
//
#include <hip/hip_runtime.h>
#include <hip/hip_bf16.h>

#define BATCH 32
#define HID 256
#define SENT 64
#define WORDS 64
#define NROWS (BATCH * SENT)   // 2048 row-blocks
#define PITCH 264              // 256 + 8 bf16 pad: breaks LDS bank conflicts, keeps 16B align

typedef __attribute__((ext_vector_type(8))) short short8;       // 8 bf16 = 4 VGPRs (MFMA A/B frag)
typedef __attribute__((ext_vector_type(4))) float float4v;      // MFMA C/D frag
typedef __attribute__((ext_vector_type(4))) unsigned short ushort4v;

__device__ __forceinline__ unsigned short f2bf(float f) {
    unsigned int u = __float_as_uint(f);
    u += 0x7fffu + ((u >> 16) & 1u);   // round-to-nearest-even
    return (unsigned short)(u >> 16);
}

__device__ __forceinline__ float bf2f(unsigned short u) {
    return __uint_as_float(((unsigned int)u) << 16);
}

__device__ __forceinline__ float tanh_fast(float x) {
    // tanh(x) = 1 - 2/(exp(2x)+1); stable at both extremes with v_exp/v_rcp
    float e = __builtin_amdgcn_exp2f(x * 2.8853900817779268f); // 2*log2(e)
    return 1.0f - 2.0f * __builtin_amdgcn_rcpf(e + 1.0f);
}

// W (256x256 f32) -> bf16 in workspace (re-done every launch; ws is re-poisoned)
__global__ void cvt_w(const float* __restrict__ W, unsigned short* __restrict__ Wb) {
    int i = blockIdx.x * 256 + threadIdx.x;  // 16384 threads, 4 elems each
    float4v v = ((const float4v*)W)[i];
    ushort4v u;
    u.x = f2bf(v.x); u.y = f2bf(v.y); u.z = f2bf(v.z); u.w = f2bf(v.w);
    ((ushort4v*)Wb)[i] = u;
}

__global__ __launch_bounds__(256, 3) void attend_fused(
    const float* __restrict__ x, const unsigned short* __restrict__ Wb,
    const float* __restrict__ bias, const float* __restrict__ ctx,
    float* __restrict__ out)
{
    __shared__ unsigned short xs[64 * PITCH];  // x block in bf16, ~33 KB
    __shared__ float wsum[4][64];              // per-wave partial row sums
    __shared__ float rinv[64];                 // 1/rowsum

    const int tid  = threadIdx.x;
    const int wave = tid >> 6;
    const int lane = tid & 63;
    const int q    = lane >> 4;   // quad id 0..3
    const int c    = lane & 15;   // col-in-tile 0..15
    const int n    = blockIdx.x;
    const int obase = wave * 64;  // this wave's 64 output columns

    // ---- stage x[n] (64x256 f32) -> bf16 LDS, coalesced float4 reads ----
    const float4v* xg = ((const float4v*)x) + (size_t)n * 4096;
#pragma unroll
    for (int i = 0; i < 16; ++i) {
        int chunk = tid + 256 * i;       // 0..4095 float4-chunks
        int w = chunk >> 6;
        int j = chunk & 63;
        float4v v = xg[chunk];
        ushort4v u;
        u.x = f2bf(v.x); u.y = f2bf(v.y); u.z = f2bf(v.z); u.w = f2bf(v.w);
        *(ushort4v*)&xs[w * PITCH + j * 4] = u;
    }
    __syncthreads();

    // ---- GEMM: acc[mt][nt] = x[64x256] * W^T tile (wave's 64 cols) ----
    float4v acc[4][4];
#pragma unroll
    for (int mt = 0; mt < 4; ++mt)
#pragma unroll
        for (int nt = 0; nt < 4; ++nt)
            acc[mt][nt] = (float4v){0.f, 0.f, 0.f, 0.f};

#pragma unroll
    for (int kt = 0; kt < 8; ++kt) {
        const int kb = kt * 32 + q * 8;  // lane's 8-elem K slice
        short8 a[4];
#pragma unroll
        for (int mt = 0; mt < 4; ++mt)
            a[mt] = *(const short8*)&xs[(mt * 16 + c) * PITCH + kb];
#pragma unroll
        for (int nt = 0; nt < 4; ++nt) {
            // B[k][n] = W[o][k]: lane reads 16B of W row o (L2-resident bf16 W)
            short8 bfrag = *(const short8*)&Wb[(size_t)(obase + nt * 16 + c) * 256 + kb];
#pragma unroll
            for (int mt = 0; mt < 4; ++mt)
                acc[mt][nt] = __builtin_amdgcn_mfma_f32_16x16x32_bf16(
                    a[mt], bfrag, acc[mt][nt], 0, 0, 0);
        }
    }

    // ---- epilogue: e = exp(tanh(acc+b)*ctx); partial row sums in-register ----
    // D layout: row = 16*mt + 4*q + reg, col = obase + 16*nt + c
    float psum[4][4];
#pragma unroll
    for (int mt = 0; mt < 4; ++mt)
#pragma unroll
        for (int r = 0; r < 4; ++r)
            psum[mt][r] = 0.f;

#pragma unroll
    for (int nt = 0; nt < 4; ++nt) {
        const int o = obase + nt * 16 + c;
        const float bb = bias[o];
        const float cc = ctx[o];
#pragma unroll
        for (int mt = 0; mt < 4; ++mt) {
#pragma unroll
            for (int r = 0; r < 4; ++r) {
                float s = tanh_fast(acc[mt][nt][r] + bb) * cc;   // |s| <= 0.0625
                float e = __builtin_amdgcn_exp2f(s * 1.4426950408889634f); // no max needed
                acc[mt][nt][r] = e;
                psum[mt][r] += e;
            }
        }
    }
    // sum across the 16 lanes of each quad (covers this wave's 64 cols)
#pragma unroll
    for (int mt = 0; mt < 4; ++mt)
#pragma unroll
        for (int r = 0; r < 4; ++r) {
            float v = psum[mt][r];
            v += __shfl_xor(v, 1);
            v += __shfl_xor(v, 2);
            v += __shfl_xor(v, 4);
            v += __shfl_xor(v, 8);
            psum[mt][r] = v;
        }
    if (c == 0) {
#pragma unroll
        for (int mt = 0; mt < 4; ++mt)
#pragma unroll
            for (int r = 0; r < 4; ++r)
                wsum[wave][mt * 16 + q * 4 + r] = psum[mt][r];
    }
    __syncthreads();
    if (tid < 64) {
        float t = wsum[0][tid] + wsum[1][tid] + wsum[2][tid] + wsum[3][tid];
        rinv[tid] = __builtin_amdgcn_rcpf(t);
    }
    __syncthreads();

    // ---- out[h] = sum_w x[w][h] * e[w][h] / rowsum[w]  (alpha never stored) ----
    float outp[4] = {0.f, 0.f, 0.f, 0.f};
#pragma unroll
    for (int mt = 0; mt < 4; ++mt) {
#pragma unroll
        for (int r = 0; r < 4; ++r) {
            const int w = mt * 16 + q * 4 + r;
            const float ri = rinv[w];
            const unsigned short* row = &xs[w * PITCH];
#pragma unroll
            for (int nt = 0; nt < 4; ++nt) {
                const int h = obase + nt * 16 + c;
                outp[nt] += bf2f(row[h]) * acc[mt][nt][r] * ri;
            }
        }
    }
#pragma unroll
    for (int nt = 0; nt < 4; ++nt) {
        float v = outp[nt];
        v += __shfl_xor(v, 16);   // combine the 4 quads' disjoint w-ranges
        v += __shfl_xor(v, 32);
        if (q == 0)
            out[(size_t)n * HID + obase + nt * 16 + c] = v;
    }
}

extern "C" void kernel_launch(void* const* d_in, const int* in_sizes, int n_in,
                              void* d_out, int out_size, void* d_ws, size_t ws_size,
                              hipStream_t stream) {
    const float* x    = (const float*)d_in[0];   // [2048, 64, 256]
    const float* W    = (const float*)d_in[1];   // [256, 256]
    const float* bias = (const float*)d_in[2];   // [256]
    const float* ctx  = (const float*)d_in[3];   // [256]
    unsigned short* Wb = (unsigned short*)d_ws;  // 128 KB bf16 W

    cvt_w<<<64, 256, 0, stream>>>(W, Wb);
    attend_fused<<<NROWS, 256, 0, stream>>>(x, Wb, bias, ctx, (float*)d_out);
}

// Round 2
// 228.445 us; speedup vs baseline: 1.0162x; 1.0162x over previous
//
#include <hip/hip_runtime.h>
#include <hip/hip_bf16.h>

#define BATCH 32
#define HID 256
#define SENT 64
#define WORDS 64
#define NROWS (BATCH * SENT)   // 2048 row-blocks
#define PITCH 264              // 256 + 8 bf16 pad; keeps 16B align, no >2-way LDS conflicts

typedef __attribute__((ext_vector_type(8))) short short8;       // 8 bf16 = 4 VGPRs (MFMA A/B frag)
typedef __attribute__((ext_vector_type(4))) float float4v;      // MFMA C/D frag
typedef __attribute__((ext_vector_type(4))) unsigned short ushort4v;

__device__ __forceinline__ float bf2f(unsigned short u) {
    return __uint_as_float(((unsigned int)u) << 16);
}

__device__ __forceinline__ unsigned int pk_bf16(float a, float b) {
    // packed RNE f32->bf16 via hip intrinsic (v_cvt_pk_bf16_f32 on gfx950)
    __hip_bfloat162 p = __float22bfloat162_rn(float2{a, b});
    return *(unsigned int*)&p;
}

__device__ __forceinline__ float tanh_fast(float x) {
    float e = __builtin_amdgcn_exp2f(x * 2.8853900817779268f); // exp(2x)
    return 1.0f - 2.0f * __builtin_amdgcn_rcpf(e + 1.0f);
}

// W (256x256 f32) -> bf16 in workspace (ws re-poisoned every launch, so redo)
__global__ void cvt_w(const float* __restrict__ W, unsigned short* __restrict__ Wb) {
    int i = blockIdx.x * 256 + threadIdx.x;
    float4v v = ((const float4v*)W)[i];
    unsigned int lo = pk_bf16(v.x, v.y), hi = pk_bf16(v.z, v.w);
    ushort4v u;
    u.x = (unsigned short)lo; u.y = (unsigned short)(lo >> 16);
    u.z = (unsigned short)hi; u.w = (unsigned short)(hi >> 16);
    ((ushort4v*)Wb)[i] = u;
}

__global__ __launch_bounds__(256, 4) void attend_fused(
    const float* __restrict__ x, const unsigned short* __restrict__ Wb,
    const float* __restrict__ bias, const float* __restrict__ ctx,
    float* __restrict__ out)
{
    __shared__ unsigned short xs[64 * PITCH];  // x block in bf16, ~33.8 KB
    __shared__ float wsum[4][64];
    __shared__ float rinv[64];

    const int tid  = threadIdx.x;
    const int wave = tid >> 6;
    const int lane = tid & 63;
    const int q    = lane >> 4;   // quad 0..3
    const int c    = lane & 15;   // col-in-tile
    const int n    = blockIdx.x;
    const int obase = wave * 64;  // this wave's 64 output columns

    // ---- hoisted epilogue constants (L2/L3 hits, issued early) ----
    float bb[4], cc[4];
#pragma unroll
    for (int nt = 0; nt < 4; ++nt) {
        bb[nt] = bias[obase + nt * 16 + c];
        cc[nt] = ctx[obase + nt * 16 + c];
    }

    // ---- stage x[n] (64x256 f32) -> bf16 LDS; phase 1: all loads in flight ----
    const float4v* xg = ((const float4v*)x) + (size_t)n * 4096;
    float4v vbuf[16];
#pragma unroll
    for (int i = 0; i < 16; ++i)
        vbuf[i] = xg[tid + 256 * i];
    // phase 2: packed cvt + LDS write
#pragma unroll
    for (int i = 0; i < 16; ++i) {
        int chunk = tid + 256 * i;
        int w = chunk >> 6;
        int j = chunk & 63;
        unsigned int lo = pk_bf16(vbuf[i].x, vbuf[i].y);
        unsigned int hi = pk_bf16(vbuf[i].z, vbuf[i].w);
        unsigned int* dst = (unsigned int*)&xs[w * PITCH + j * 4];
        dst[0] = lo; dst[1] = hi;
    }
    __syncthreads();

    // ---- GEMM: acc = x[64x256] * W^T (wave's 64 cols), B double-buffered ----
    float4v acc[4][4];
#pragma unroll
    for (int mt = 0; mt < 4; ++mt)
#pragma unroll
        for (int nt = 0; nt < 4; ++nt)
            acc[mt][nt] = (float4v){0.f, 0.f, 0.f, 0.f};

    const unsigned short* wrow[4];
#pragma unroll
    for (int nt = 0; nt < 4; ++nt)
        wrow[nt] = &Wb[(size_t)(obase + nt * 16 + c) * 256 + q * 8];

    short8 bcur[4], bnxt[4];
#pragma unroll
    for (int nt = 0; nt < 4; ++nt)
        bcur[nt] = *(const short8*)(wrow[nt]);

#pragma unroll
    for (int kt = 0; kt < 8; ++kt) {
        if (kt < 7) {
#pragma unroll
            for (int nt = 0; nt < 4; ++nt)
                bnxt[nt] = *(const short8*)(wrow[nt] + (kt + 1) * 32);
        }
        const int kb = kt * 32 + q * 8;
        short8 a[4];
#pragma unroll
        for (int mt = 0; mt < 4; ++mt)
            a[mt] = *(const short8*)&xs[(mt * 16 + c) * PITCH + kb];
#pragma unroll
        for (int nt = 0; nt < 4; ++nt)
#pragma unroll
            for (int mt = 0; mt < 4; ++mt)
                acc[mt][nt] = __builtin_amdgcn_mfma_f32_16x16x32_bf16(
                    a[mt], bcur[nt], acc[mt][nt], 0, 0, 0);
#pragma unroll
        for (int nt = 0; nt < 4; ++nt)
            bcur[nt] = bnxt[nt];
    }

    // ---- epilogue: e = exp(tanh(acc+b)*ctx); row sums in-register ----
    // D layout: row = 16*mt + 4*q + reg, col = obase + 16*nt + c
    float psum[4][4];
#pragma unroll
    for (int mt = 0; mt < 4; ++mt)
#pragma unroll
        for (int r = 0; r < 4; ++r)
            psum[mt][r] = 0.f;

#pragma unroll
    for (int nt = 0; nt < 4; ++nt) {
#pragma unroll
        for (int mt = 0; mt < 4; ++mt) {
#pragma unroll
            for (int r = 0; r < 4; ++r) {
                float s = tanh_fast(acc[mt][nt][r] + bb[nt]) * cc[nt];   // |s| <= ~0.0625
                float e = __builtin_amdgcn_exp2f(s * 1.4426950408889634f); // no max-sub needed
                acc[mt][nt][r] = e;
                psum[mt][r] += e;
            }
        }
    }
#pragma unroll
    for (int mt = 0; mt < 4; ++mt)
#pragma unroll
        for (int r = 0; r < 4; ++r) {
            float v = psum[mt][r];
            v += __shfl_xor(v, 1);
            v += __shfl_xor(v, 2);
            v += __shfl_xor(v, 4);
            v += __shfl_xor(v, 8);
            psum[mt][r] = v;
        }
    if (c == 0) {
#pragma unroll
        for (int mt = 0; mt < 4; ++mt)
#pragma unroll
            for (int r = 0; r < 4; ++r)
                wsum[wave][mt * 16 + q * 4 + r] = psum[mt][r];
    }
    __syncthreads();
    if (tid < 64) {
        float t = wsum[0][tid] + wsum[1][tid] + wsum[2][tid] + wsum[3][tid];
        rinv[tid] = __builtin_amdgcn_rcpf(t);
    }
    __syncthreads();

    // ---- out[h] = sum_w x[w][h] * e[w][h] * rinv[w] ----
    float ri[4][4];
#pragma unroll
    for (int mt = 0; mt < 4; ++mt)
#pragma unroll
        for (int r = 0; r < 4; ++r)
            ri[mt][r] = rinv[mt * 16 + q * 4 + r];

    float outp[4] = {0.f, 0.f, 0.f, 0.f};
#pragma unroll
    for (int mt = 0; mt < 4; ++mt) {
#pragma unroll
        for (int r = 0; r < 4; ++r) {
            const int w = mt * 16 + q * 4 + r;
            const unsigned short* row = &xs[w * PITCH];
            const float wgt = ri[mt][r];
#pragma unroll
            for (int nt = 0; nt < 4; ++nt) {
                const int h = obase + nt * 16 + c;
                outp[nt] += bf2f(row[h]) * (acc[mt][nt][r] * wgt);
            }
        }
    }
#pragma unroll
    for (int nt = 0; nt < 4; ++nt) {
        float v = outp[nt];
        v += __shfl_xor(v, 16);   // combine the 4 quads' disjoint w-ranges
        v += __shfl_xor(v, 32);
        if (q == 0)
            out[(size_t)n * HID + obase + nt * 16 + c] = v;
    }
}

extern "C" void kernel_launch(void* const* d_in, const int* in_sizes, int n_in,
                              void* d_out, int out_size, void* d_ws, size_t ws_size,
                              hipStream_t stream) {
    const float* x    = (const float*)d_in[0];   // [2048, 64, 256]
    const float* W    = (const float*)d_in[1];   // [256, 256]
    const float* bias = (const float*)d_in[2];   // [256]
    const float* ctx  = (const float*)d_in[3];   // [256]
    unsigned short* Wb = (unsigned short*)d_ws;  // 128 KB bf16 W

    cvt_w<<<64, 256, 0, stream>>>(W, Wb);
    attend_fused<<<NROWS, 256, 0, stream>>>(x, Wb, bias, ctx, (float*)d_out);
}